// Round 9
// baseline (108.457 us; speedup 1.0000x reference)
//
#include <hip/hip_runtime.h>
#include <hip/hip_bf16.h>
#include <stdint.h>

// ---------------------------------------------------------------------------
// MultiHeadCrossAttention, B=8 C=512 H=W=64 nh=8 d=64.
// Index algebra (t = h*64+w, f = t*512+c):
//   n = h>>3 (the HEAD), dd = (h&7)*8 + (w>>3), hh = (w&7)*8 + (c>>6), ww = c&63
// With e = hh&7, g = hh>>3: token j within slab (b,n): j = 8*dd + g.
// q broadcast over tokens -> scores rank-1:
//   scores[qq,kk] = qs[b][e*64+qq] * K2[b,n,g][e*64+kk]
//   qs = (guide@Wq^T + bq)*0.125 ; K2 = hrsum@Wk^T + 64*bk
//   hrsum[b,n,g,c'] = sum_{j==g mod 8} hid[b,c',n*512+j]
// attended[qq,dd] = sum_kk P[qq,kk] * V[e*64+kk][j(dd,g)]
//   V[c][j] = sum_c' Wv[c][c'] * hid[b][c'][n*512+j] + bv[c]
// out[b][n*64+dd][g*8+e][qq]
//
// r9: P-EXTRACTION. P = softmax(rank-1(qs,K2)) is independent of V -> compute
// all 4096 64x64 P matrices (bf16, 33.5MB) in a dedicated kernel k_pmat with
// coalesced stores in MFMA-B-fragment layout [slab][g][e][qq][kk]. k_fused
// phase 2 loses all exp/shfl/f2bf VALU work: Vp spill + 8 P-fragment loads +
// 32 MFMA + stores. Diagnostic: if k_fused stays ~55us, the V-GEMM shape is
// the binding constraint; if it drops to ~40, phase-2 VALU was the sink.
// ---------------------------------------------------------------------------

typedef __attribute__((ext_vector_type(8))) short bf16x8_t;
typedef __attribute__((ext_vector_type(4))) float f32x4_t;

__device__ __forceinline__ unsigned short f2bf(float f) {
  unsigned int u = __float_as_uint(f);
  u += 0x7FFFu + ((u >> 16) & 1u);
  return (unsigned short)(u >> 16);
}

__device__ __forceinline__ void gload16(const void* g, void* lds) {
  __builtin_amdgcn_global_load_lds(
      (const __attribute__((address_space(1))) unsigned int*)g,
      (__attribute__((address_space(3))) unsigned int*)lds, 16, 0, 0);
}

// ---------------- kernel 2: transpose hid -> XT (bf16) + hrsum (fp32) -------
// blocks [0,1024): (b,n,cb,rhalf) -> 32 c' rows x 512 j. [1024,1040): Wv cvt.
__global__ __launch_bounds__(256) void k_trans(const float* __restrict__ hid,
                                               unsigned short* __restrict__ XT,
                                               float* __restrict__ hrsum,
                                               const float* __restrict__ Wv,
                                               unsigned short* __restrict__ Wvb) {
  int bid = blockIdx.x;
  int tid = threadIdx.x;
  if (bid >= 1024) {
    int blk = bid - 1024;
#pragma unroll
    for (int i = 0; i < 16; ++i) {
      int idx = blk * 4096 + i * 256 + tid;
      float4 v = ((const float4*)Wv)[idx];
      ushort4 o;
      o.x = f2bf(v.x); o.y = f2bf(v.y); o.z = f2bf(v.z); o.w = f2bf(v.w);
      ((ushort4*)Wvb)[idx] = o;
    }
    return;
  }
  int rh = bid & 1, cb = (bid >> 1) & 7, n = (bid >> 4) & 7, b = bid >> 7;
  __shared__ float T[32][65];
  __shared__ float hsred[32][8];
  ((float*)hsred)[tid] = 0.f;

  float part[2][4];
#pragma unroll
  for (int m = 0; m < 2; ++m)
#pragma unroll
    for (int i = 0; i < 4; ++i) part[m][i] = 0.f;

  const int f4 = tid & 15;
  const int r0 = tid >> 4;
  const float* srcbase = hid + (size_t)(b * 512 + cb * 64 + rh * 32) * 4096 + n * 512;
  unsigned short* xtbase =
      XT + (size_t)(b * 8 + n) * 512 * 512 + cb * 64 + rh * 32;

  float4 va[2], vb2[2];
#pragma unroll
  for (int m = 0; m < 2; ++m)
    va[m] = *(const float4*)(srcbase + (size_t)(r0 + 16 * m) * 4096 + f4 * 4);

#define TSTEP(JC, CUR, NXT, LAST)                                              \
  do {                                                                         \
    _Pragma("unroll")                                                          \
    for (int m_ = 0; m_ < 2; ++m_) {                                           \
      int r_ = r0 + 16 * m_;                                                   \
      T[r_][f4 * 4 + 0] = CUR[m_].x;  T[r_][f4 * 4 + 1] = CUR[m_].y;           \
      T[r_][f4 * 4 + 2] = CUR[m_].z;  T[r_][f4 * 4 + 3] = CUR[m_].w;           \
      part[m_][0] += CUR[m_].x; part[m_][1] += CUR[m_].y;                      \
      part[m_][2] += CUR[m_].z; part[m_][3] += CUR[m_].w;                      \
    }                                                                          \
    if (!(LAST)) {                                                             \
      _Pragma("unroll")                                                        \
      for (int m_ = 0; m_ < 2; ++m_)                                           \
        NXT[m_] = *(const float4*)(srcbase + (size_t)(r0 + 16 * m_) * 4096 +   \
                                   ((JC) + 1) * 64 + f4 * 4);                  \
    }                                                                          \
    __syncthreads();                                                           \
    {                                                                          \
      int jl_ = tid >> 2, o_ = tid & 3;                                        \
      unsigned short t0 = f2bf(T[o_ * 8 + 0][jl_]);                            \
      unsigned short t1 = f2bf(T[o_ * 8 + 1][jl_]);                            \
      unsigned short t2 = f2bf(T[o_ * 8 + 2][jl_]);                            \
      unsigned short t3 = f2bf(T[o_ * 8 + 3][jl_]);                            \
      unsigned short t4 = f2bf(T[o_ * 8 + 4][jl_]);                            \
      unsigned short t5 = f2bf(T[o_ * 8 + 5][jl_]);                            \
      unsigned short t6 = f2bf(T[o_ * 8 + 6][jl_]);                            \
      unsigned short t7 = f2bf(T[o_ * 8 + 7][jl_]);                            \
      uint4 pk_;                                                               \
      pk_.x = (unsigned)t0 | ((unsigned)t1 << 16);                             \
      pk_.y = (unsigned)t2 | ((unsigned)t3 << 16);                             \
      pk_.z = (unsigned)t4 | ((unsigned)t5 << 16);                             \
      pk_.w = (unsigned)t6 | ((unsigned)t7 << 16);                             \
      *(uint4*)(xtbase + (size_t)((JC) * 64 + jl_) * 512 + o_ * 8) = pk_;      \
    }                                                                          \
    __syncthreads();                                                           \
  } while (0)

  TSTEP(0, va, vb2, 0);
  TSTEP(1, vb2, va, 0);
  TSTEP(2, va, vb2, 0);
  TSTEP(3, vb2, va, 0);
  TSTEP(4, va, vb2, 0);
  TSTEP(5, vb2, va, 0);
  TSTEP(6, va, vb2, 0);
  TSTEP(7, vb2, va, 1);
#undef TSTEP

  {
    int gbase = (f4 & 1) * 4;
#pragma unroll
    for (int m = 0; m < 2; ++m) {
      int r = r0 + 16 * m;
#pragma unroll
      for (int i = 0; i < 4; ++i) atomicAdd(&hsred[r][gbase + i], part[m][i]);
    }
  }
  __syncthreads();
  float* hout = hrsum + (size_t)(b * 8 + n) * 4096 + cb * 64 + rh * 32;
  {
    int g = tid >> 5, r = tid & 31;
    hout[(size_t)g * 512 + r] = hsred[r][g];
  }
}

// ---------------- kernel 3: K2 = hrsum@Wk^T + 64*bk ; qs = (guide@Wq^T+bq)/8 -
__global__ __launch_bounds__(256) void k_k2(const float* __restrict__ hrsum,
                                            const float* __restrict__ Wk,
                                            const float* __restrict__ bk,
                                            const float* __restrict__ guide,
                                            const float* __restrict__ Wq,
                                            const float* __restrict__ bq,
                                            float* __restrict__ K2,
                                            float* __restrict__ qs) {
  int bid = blockIdx.x;
  int rt = bid >> 4, ct = bid & 15;
  bool isQ = (rt == 16);
  const float* A = isQ ? guide : (hrsum + (size_t)rt * 32 * 512);
  const float* Bm = isQ ? Wq : Wk;
  int arows = isQ ? 8 : 32;
  int tid = threadIdx.x;
  __shared__ float Ah[32][36];
  __shared__ float Bh[32][36];
  int r = tid >> 3, f = tid & 7;
  int oy = (tid >> 4) * 2, ox = (tid & 15) * 2;
  float a00 = 0.f, a01 = 0.f, a10 = 0.f, a11 = 0.f;

  for (int kc = 0; kc < 16; ++kc) {
    __syncthreads();
    float4 av = (r < arows) ? *(const float4*)(A + (size_t)r * 512 + kc * 32 + f * 4)
                            : make_float4(0.f, 0.f, 0.f, 0.f);
    *(float4*)(&Ah[r][f * 4]) = av;
    float4 bv = *(const float4*)(Bm + (size_t)(ct * 32 + r) * 512 + kc * 32 + f * 4);
    *(float4*)(&Bh[r][f * 4]) = bv;
    __syncthreads();
#pragma unroll
    for (int kk = 0; kk < 32; kk += 4) {
      float4 x0 = *(float4*)(&Ah[oy][kk]);
      float4 x1 = *(float4*)(&Ah[oy + 1][kk]);
      float4 y0 = *(float4*)(&Bh[ox][kk]);
      float4 y1 = *(float4*)(&Bh[ox + 1][kk]);
      a00 += x0.x * y0.x + x0.y * y0.y + x0.z * y0.z + x0.w * y0.w;
      a01 += x0.x * y1.x + x0.y * y1.y + x0.z * y1.z + x0.w * y1.w;
      a10 += x1.x * y0.x + x1.y * y0.y + x1.z * y0.z + x1.w * y0.w;
      a11 += x1.x * y1.x + x1.y * y1.y + x1.z * y1.z + x1.w * y1.w;
    }
  }
  int c0 = ct * 32 + ox;
  if (!isQ) {
    int row0 = rt * 32 + oy;
    K2[(size_t)row0 * 512 + c0]           = a00 + 64.f * bk[c0];
    K2[(size_t)row0 * 512 + c0 + 1]       = a01 + 64.f * bk[c0 + 1];
    K2[(size_t)(row0 + 1) * 512 + c0]     = a10 + 64.f * bk[c0];
    K2[(size_t)(row0 + 1) * 512 + c0 + 1] = a11 + 64.f * bk[c0 + 1];
  } else if (oy < 8) {
    const float scale = 0.125f;
    qs[(size_t)oy * 512 + c0]           = (a00 + bq[c0]) * scale;
    qs[(size_t)oy * 512 + c0 + 1]       = (a01 + bq[c0 + 1]) * scale;
    qs[(size_t)(oy + 1) * 512 + c0]     = (a10 + bq[c0]) * scale;
    qs[(size_t)(oy + 1) * 512 + c0 + 1] = (a11 + bq[c0 + 1]) * scale;
  }
}

// ---------------- kernel 3b: P matrices -------------------------------------
// grid 512 = (slab,g); 512 threads = 8 waves, wave w = e.
// P[slab][g][e][qq 64][kk 64] bf16, row-major kk-contiguous (128B rows) --
// exactly the MFMA B-fragment layout k_fused loads 16B at a time.
__global__ __launch_bounds__(512) void k_pmat(const float* __restrict__ K2,
                                              const float* __restrict__ qs,
                                              unsigned short* __restrict__ P) {
  int p = blockIdx.x;
  int slab = p >> 3, g = p & 7;
  int b = slab >> 3;
  int tid = threadIdx.x;
  int w = tid >> 6, l = tid & 63;

  float alpha = qs[(size_t)b * 512 + w * 64 + l];              // lane = qq
  float beta  = K2[(size_t)(slab * 8 + g) * 512 + w * 64 + l]; // lane = kk

  float bmax = beta, bmin = beta;
#pragma unroll
  for (int o = 32; o >= 1; o >>= 1) {
    bmax = fmaxf(bmax, __shfl_xor(bmax, o));
    bmin = fminf(bmin, __shfl_xor(bmin, o));
  }
  float m = alpha >= 0.f ? alpha * bmax : alpha * bmin;
  float ssum = 0.f;
#pragma unroll 8
  for (int kk = 0; kk < 64; ++kk)
    ssum += __expf(fmaf(alpha, __shfl(beta, kk), -m));
  float inv = 1.0f / ssum;

  unsigned short* Pb = P + (((size_t)(slab * 8 + g)) * 8 + w) * 4096;
  const int qrow = l >> 3, koff = (l & 7) * 8;
#pragma unroll
  for (int p8 = 0; p8 < 8; ++p8) {
    int qq = p8 * 8 + qrow;
    float aq = __shfl(alpha, qq);
    float mq = __shfl(m, qq);
    float iq = __shfl(inv, qq);
    unsigned short v[8];
#pragma unroll
    for (int i = 0; i < 8; ++i) {
      float bk = __shfl(beta, koff + i);
      v[i] = f2bf(__expf(fmaf(aq, bk, -mq)) * iq);
    }
    uint4 pk;
    pk.x = (unsigned)v[0] | ((unsigned)v[1] << 16);
    pk.y = (unsigned)v[2] | ((unsigned)v[3] << 16);
    pk.z = (unsigned)v[4] | ((unsigned)v[5] << 16);
    pk.w = (unsigned)v[6] | ((unsigned)v[7] << 16);
    *(uint4*)(Pb + qq * 64 + koff) = pk;   // wave store = 1KB contiguous
  }
}

// ---------------- kernel 4: fused V-GEMM + PV (P precomputed) ---------------
// grid 512 = slab(64) * g(8), XCD-grouped; 512 threads = 8 waves, wave w = e.
// LDS 64KB: X-tile [8 kc][64 j][128B] during GEMM; per-wave V slices after.
__global__ __launch_bounds__(512, 4) void k_fused(
    const unsigned short* __restrict__ XT, const unsigned short* __restrict__ Wvb,
    const unsigned short* __restrict__ P, const float* __restrict__ bv,
    float* __restrict__ out) {
  int p = blockIdx.x;
  int xcd = p & 7, idx = p >> 3;
  int slab = xcd * 8 + (idx & 7);
  int g = idx >> 3;
  int n = slab & 7, b = slab >> 3;

  int tid = threadIdx.x;
  int w = tid >> 6, l = tid & 63;
  int l15 = l & 15, l4 = l >> 4, lr = l >> 3, lc = l & 7;

  __shared__ __align__(16) unsigned char smem[65536];

  const unsigned swzel = (unsigned)((lc ^ lr) << 3);  // pre-swizzled src col
  const unsigned short* bsrc = XT + (size_t)slab * 512 * 512;
  const unsigned short* wbase = Wvb + (size_t)(w * 64 + l15) * 512 + l4 * 8;
  const int brow = 8 * (w * 8 + lr) + g;

  // ---- stage B once: 8 x global_load_lds (16B) per thread ----
#pragma unroll
  for (int i = 0; i < 8; ++i)
    gload16(bsrc + (size_t)brow * 512 + i * 64 + swzel, smem + i * 8192 + w * 1024);

  float bvreg = bv[w * 64 + l];   // lane = kk

  f32x4_t acc[4][4];
#pragma unroll
  for (int i = 0; i < 4; ++i)
#pragma unroll
    for (int j = 0; j < 4; ++j) acc[i][j] = (f32x4_t){0.f, 0.f, 0.f, 0.f};

  __syncthreads();   // B resident for the whole K-loop

  // ---- barrier-free K-loop: 16 K32-steps, depth-2 af prefetch ----
  bf16x8_t af[2][4];
#pragma unroll
  for (int mt = 0; mt < 4; ++mt)
    af[0][mt] = *(const bf16x8_t*)(wbase + mt * 16 * 512);

#pragma unroll
  for (int s = 0; s < 16; ++s) {
    if (s < 15) {
#pragma unroll
      for (int mt = 0; mt < 4; ++mt)
        af[(s + 1) & 1][mt] =
            *(const bf16x8_t*)(wbase + mt * 16 * 512 + (s + 1) * 32);
    }
    unsigned char* Bb = smem + (s >> 1) * 8192;
    bf16x8_t bfr[4];
#pragma unroll
    for (int nt = 0; nt < 4; ++nt) {
      unsigned row = (unsigned)(nt * 16 + l15);
      bfr[nt] = *(const bf16x8_t*)(Bb + row * 128 +
                ((unsigned)((s & 1) * 64 + l4 * 16) ^ ((row & 7) << 4)));
    }
#pragma unroll
    for (int mt = 0; mt < 4; ++mt)
#pragma unroll
      for (int nt = 0; nt < 4; ++nt)
        acc[mt][nt] = __builtin_amdgcn_mfma_f32_16x16x32_bf16(
            af[s & 1][mt], bfr[nt], acc[mt][nt], 0, 0, 0);
  }

  // ---- issue P-fragment loads (independent of spill; latency hides) ----
  const unsigned short* Pb = P + (((size_t)(slab * 8 + g)) * 8 + w) * 4096;
  bf16x8_t pb[2][4];
#pragma unroll
  for (int ks = 0; ks < 2; ++ks)
#pragma unroll
    for (int nt = 0; nt < 4; ++nt)
      pb[ks][nt] = *(const bf16x8_t*)(Pb + (nt * 16 + l15) * 64 + ks * 32 + l4 * 8);

  __syncthreads();   // all waves done reading the X-tile; safe to overlay

  // ---- spill V + bias -> wave-private Vp[dd][kk] bf16 (XOR-swizzled) ----
  // acc[mt][nt] reg r: kk = mt*16 + l4*4 + r, dd = nt*16 + l15.
  unsigned char* Vp = smem + w * 8192;
#pragma unroll
  for (int mt = 0; mt < 4; ++mt) {
    float bq0 = __shfl(bvreg, mt * 16 + l4 * 4 + 0);
    float bq1 = __shfl(bvreg, mt * 16 + l4 * 4 + 1);
    float bq2 = __shfl(bvreg, mt * 16 + l4 * 4 + 2);
    float bq3 = __shfl(bvreg, mt * 16 + l4 * 4 + 3);
#pragma unroll
    for (int nt = 0; nt < 4; ++nt) {
      unsigned dd = (unsigned)(nt * 16 + l15);
      uint2 pk;
      pk.x = (unsigned)f2bf(acc[mt][nt][0] + bq0) |
             ((unsigned)f2bf(acc[mt][nt][1] + bq1) << 16);
      pk.y = (unsigned)f2bf(acc[mt][nt][2] + bq2) |
             ((unsigned)f2bf(acc[mt][nt][3] + bq3) << 16);
      *(uint2*)(Vp + dd * 128 +
                ((unsigned)(mt * 32 + l4 * 8) ^ ((dd & 7) << 4))) = pk;
    }
  }

  // ---- PV: D[m=dd][n=qq], A = Vp, B = precomputed P fragments ----
  f32x4_t acc2[4][4];
#pragma unroll
  for (int i = 0; i < 4; ++i)
#pragma unroll
    for (int j = 0; j < 4; ++j) acc2[i][j] = (f32x4_t){0.f, 0.f, 0.f, 0.f};

#pragma unroll
  for (int ks = 0; ks < 2; ++ks) {
    bf16x8_t va[4];
#pragma unroll
    for (int mt = 0; mt < 4; ++mt) {   // A[dd][kk] from Vp
      unsigned dd = (unsigned)(mt * 16 + l15);
      va[mt] = *(const bf16x8_t*)(Vp + dd * 128 +
                ((unsigned)(ks * 64 + l4 * 16) ^ ((dd & 7) << 4)));
    }
#pragma unroll
    for (int mt = 0; mt < 4; ++mt)
#pragma unroll
      for (int nt = 0; nt < 4; ++nt)
        acc2[mt][nt] = __builtin_amdgcn_mfma_f32_16x16x32_bf16(
            va[mt], pb[ks][nt], acc2[mt][nt], 0, 0, 0);
  }

  // ---- stores: D[m=dd][n=qq], contiguous 64B per 16 lanes ----
#pragma unroll
  for (int mt = 0; mt < 4; ++mt) {
#pragma unroll
    for (int r = 0; r < 4; ++r) {
      int dd = mt * 16 + l4 * 4 + r;
      size_t base = (((size_t)(b * 512 + n * 64 + dd)) * 64 + (g * 8 + w)) * 64;
#pragma unroll
      for (int nt = 0; nt < 4; ++nt)
        out[base + nt * 16 + l15] = acc2[mt][nt][r];
    }
  }
}

// ---------------------------------------------------------------------------
extern "C" void kernel_launch(void* const* d_in, const int* in_sizes, int n_in,
                              void* d_out, int out_size, void* d_ws, size_t ws_size,
                              hipStream_t stream) {
  const float* guide = (const float*)d_in[0];
  const float* hid   = (const float*)d_in[1];
  const float* Wq    = (const float*)d_in[2];
  const float* bq    = (const float*)d_in[3];
  const float* Wk    = (const float*)d_in[4];
  const float* bk    = (const float*)d_in[5];
  const float* Wv    = (const float*)d_in[6];
  const float* bv    = (const float*)d_in[7];
  float* out = (float*)d_out;

  char* ws = (char*)d_ws;
  unsigned short* XT  = (unsigned short*)(ws);             // 33,554,432 B
  unsigned short* Wvb = (unsigned short*)(ws + 33554432);  //    524,288 B
  float* hrsum        = (float*)(ws + 34078720);           //  1,048,576 B
  float* K2           = (float*)(ws + 35127296);           //  1,048,576 B
  float* qs           = (float*)(ws + 36175872);           //     16,384 B
  unsigned short* P   = (unsigned short*)(ws + 36192256);  // 33,554,432 B

  k_trans<<<1040, 256, 0, stream>>>(hid, XT, hrsum, Wv, Wvb);
  k_k2<<<272, 256, 0, stream>>>(hrsum, Wk, bk, guide, Wq, bq, K2, qs);
  k_pmat<<<512, 512, 0, stream>>>(K2, qs, P);
  k_fused<<<512, 512, 0, stream>>>(XT, Wvb, P, bv, out);
}

// Round 10
// 84.196 us; speedup vs baseline: 1.2882x; 1.2882x over previous
//
#include <hip/hip_runtime.h>
#include <hip/hip_bf16.h>
#include <stdint.h>

// ---------------------------------------------------------------------------
// MultiHeadCrossAttention, B=8 C=512 H=W=64 nh=8 d=64.
// Index algebra (t = h*64+w, f = t*512+c):
//   n = h>>3 (the HEAD), dd = (h&7)*8 + (w>>3), hh = (w&7)*8 + (c>>6), ww = c&63
// With e = hh&7, g = hh>>3: token j within slab (b,n): j = 8*dd + g.
// q broadcast over tokens -> scores rank-1:
//   scores[qq,kk] = qs[b][e*64+qq] * K2[b,n,g][e*64+kk]
//   qs = (guide@Wq^T + bq)*0.125 ; K2 = hrsum@Wk^T + 64*bk
//   hrsum[b,n,g,c'] = sum_{j==g mod 8} hid[b,c',n*512+j]
// attended[qq,dd] = sum_kk P[qq,kk] * V[e*64+kk][j(dd,g)]
//   V[c][j] = sum_c' Wv[c][c'] * hid[b][c'][n*512+j] + bv[c]
// out[b][n*64+dd][g*8+e][qq]
//
// r10: 2 SLABS PER BLOCK. r2-r9 showed the 1-slab k_fused is pinned at ~54us
// (360 TF = the m97-structure point at this FLOP scale) with all pipes <13% —
// ILP-bound, not pipe-bound. Doubling per-step MFMA density (32 MFMA/step,
// shared af) amortizes load latency under the matrix-pipe burst. Grid 256 =
// 1 block/CU, LDS 128KB, reg cap 256 (launch_bounds 512,2). P/k_pmat reverted.
// ---------------------------------------------------------------------------

typedef __attribute__((ext_vector_type(8))) short bf16x8_t;
typedef __attribute__((ext_vector_type(4))) float f32x4_t;

__device__ __forceinline__ unsigned short f2bf(float f) {
  unsigned int u = __float_as_uint(f);
  u += 0x7FFFu + ((u >> 16) & 1u);
  return (unsigned short)(u >> 16);
}

__device__ __forceinline__ void gload16(const void* g, void* lds) {
  __builtin_amdgcn_global_load_lds(
      (const __attribute__((address_space(1))) unsigned int*)g,
      (__attribute__((address_space(3))) unsigned int*)lds, 16, 0, 0);
}

// ---------------- kernel 2: transpose hid -> XT (bf16) + hrsum (fp32) -------
// blocks [0,1024): (b,n,cb,rhalf) -> 32 c' rows x 512 j. [1024,1040): Wv cvt.
__global__ __launch_bounds__(256) void k_trans(const float* __restrict__ hid,
                                               unsigned short* __restrict__ XT,
                                               float* __restrict__ hrsum,
                                               const float* __restrict__ Wv,
                                               unsigned short* __restrict__ Wvb) {
  int bid = blockIdx.x;
  int tid = threadIdx.x;
  if (bid >= 1024) {
    int blk = bid - 1024;
#pragma unroll
    for (int i = 0; i < 16; ++i) {
      int idx = blk * 4096 + i * 256 + tid;
      float4 v = ((const float4*)Wv)[idx];
      ushort4 o;
      o.x = f2bf(v.x); o.y = f2bf(v.y); o.z = f2bf(v.z); o.w = f2bf(v.w);
      ((ushort4*)Wvb)[idx] = o;
    }
    return;
  }
  int rh = bid & 1, cb = (bid >> 1) & 7, n = (bid >> 4) & 7, b = bid >> 7;
  __shared__ float T[32][65];
  __shared__ float hsred[32][8];
  ((float*)hsred)[tid] = 0.f;

  float part[2][4];
#pragma unroll
  for (int m = 0; m < 2; ++m)
#pragma unroll
    for (int i = 0; i < 4; ++i) part[m][i] = 0.f;

  const int f4 = tid & 15;
  const int r0 = tid >> 4;
  const float* srcbase = hid + (size_t)(b * 512 + cb * 64 + rh * 32) * 4096 + n * 512;
  unsigned short* xtbase =
      XT + (size_t)(b * 8 + n) * 512 * 512 + cb * 64 + rh * 32;

  float4 va[2], vb2[2];
#pragma unroll
  for (int m = 0; m < 2; ++m)
    va[m] = *(const float4*)(srcbase + (size_t)(r0 + 16 * m) * 4096 + f4 * 4);

#define TSTEP(JC, CUR, NXT, LAST)                                              \
  do {                                                                         \
    _Pragma("unroll")                                                          \
    for (int m_ = 0; m_ < 2; ++m_) {                                           \
      int r_ = r0 + 16 * m_;                                                   \
      T[r_][f4 * 4 + 0] = CUR[m_].x;  T[r_][f4 * 4 + 1] = CUR[m_].y;           \
      T[r_][f4 * 4 + 2] = CUR[m_].z;  T[r_][f4 * 4 + 3] = CUR[m_].w;           \
      part[m_][0] += CUR[m_].x; part[m_][1] += CUR[m_].y;                      \
      part[m_][2] += CUR[m_].z; part[m_][3] += CUR[m_].w;                      \
    }                                                                          \
    if (!(LAST)) {                                                             \
      _Pragma("unroll")                                                        \
      for (int m_ = 0; m_ < 2; ++m_)                                           \
        NXT[m_] = *(const float4*)(srcbase + (size_t)(r0 + 16 * m_) * 4096 +   \
                                   ((JC) + 1) * 64 + f4 * 4);                  \
    }                                                                          \
    __syncthreads();                                                           \
    {                                                                          \
      int jl_ = tid >> 2, o_ = tid & 3;                                        \
      unsigned short t0 = f2bf(T[o_ * 8 + 0][jl_]);                            \
      unsigned short t1 = f2bf(T[o_ * 8 + 1][jl_]);                            \
      unsigned short t2 = f2bf(T[o_ * 8 + 2][jl_]);                            \
      unsigned short t3 = f2bf(T[o_ * 8 + 3][jl_]);                            \
      unsigned short t4 = f2bf(T[o_ * 8 + 4][jl_]);                            \
      unsigned short t5 = f2bf(T[o_ * 8 + 5][jl_]);                            \
      unsigned short t6 = f2bf(T[o_ * 8 + 6][jl_]);                            \
      unsigned short t7 = f2bf(T[o_ * 8 + 7][jl_]);                            \
      uint4 pk_;                                                               \
      pk_.x = (unsigned)t0 | ((unsigned)t1 << 16);                             \
      pk_.y = (unsigned)t2 | ((unsigned)t3 << 16);                             \
      pk_.z = (unsigned)t4 | ((unsigned)t5 << 16);                             \
      pk_.w = (unsigned)t6 | ((unsigned)t7 << 16);                             \
      *(uint4*)(xtbase + (size_t)((JC) * 64 + jl_) * 512 + o_ * 8) = pk_;      \
    }                                                                          \
    __syncthreads();                                                           \
  } while (0)

  TSTEP(0, va, vb2, 0);
  TSTEP(1, vb2, va, 0);
  TSTEP(2, va, vb2, 0);
  TSTEP(3, vb2, va, 0);
  TSTEP(4, va, vb2, 0);
  TSTEP(5, vb2, va, 0);
  TSTEP(6, va, vb2, 0);
  TSTEP(7, vb2, va, 1);
#undef TSTEP

  {
    int gbase = (f4 & 1) * 4;
#pragma unroll
    for (int m = 0; m < 2; ++m) {
      int r = r0 + 16 * m;
#pragma unroll
      for (int i = 0; i < 4; ++i) atomicAdd(&hsred[r][gbase + i], part[m][i]);
    }
  }
  __syncthreads();
  float* hout = hrsum + (size_t)(b * 8 + n) * 4096 + cb * 64 + rh * 32;
  {
    int g = tid >> 5, r = tid & 31;
    hout[(size_t)g * 512 + r] = hsred[r][g];
  }
}

// ---------------- kernel 3: K2 = hrsum@Wk^T + 64*bk ; qs = (guide@Wq^T+bq)/8 -
__global__ __launch_bounds__(256) void k_k2(const float* __restrict__ hrsum,
                                            const float* __restrict__ Wk,
                                            const float* __restrict__ bk,
                                            const float* __restrict__ guide,
                                            const float* __restrict__ Wq,
                                            const float* __restrict__ bq,
                                            float* __restrict__ K2,
                                            float* __restrict__ qs) {
  int bid = blockIdx.x;
  int rt = bid >> 4, ct = bid & 15;
  bool isQ = (rt == 16);
  const float* A = isQ ? guide : (hrsum + (size_t)rt * 32 * 512);
  const float* Bm = isQ ? Wq : Wk;
  int arows = isQ ? 8 : 32;
  int tid = threadIdx.x;
  __shared__ float Ah[32][36];
  __shared__ float Bh[32][36];
  int r = tid >> 3, f = tid & 7;
  int oy = (tid >> 4) * 2, ox = (tid & 15) * 2;
  float a00 = 0.f, a01 = 0.f, a10 = 0.f, a11 = 0.f;

  for (int kc = 0; kc < 16; ++kc) {
    __syncthreads();
    float4 av = (r < arows) ? *(const float4*)(A + (size_t)r * 512 + kc * 32 + f * 4)
                            : make_float4(0.f, 0.f, 0.f, 0.f);
    *(float4*)(&Ah[r][f * 4]) = av;
    float4 bv = *(const float4*)(Bm + (size_t)(ct * 32 + r) * 512 + kc * 32 + f * 4);
    *(float4*)(&Bh[r][f * 4]) = bv;
    __syncthreads();
#pragma unroll
    for (int kk = 0; kk < 32; kk += 4) {
      float4 x0 = *(float4*)(&Ah[oy][kk]);
      float4 x1 = *(float4*)(&Ah[oy + 1][kk]);
      float4 y0 = *(float4*)(&Bh[ox][kk]);
      float4 y1 = *(float4*)(&Bh[ox + 1][kk]);
      a00 += x0.x * y0.x + x0.y * y0.y + x0.z * y0.z + x0.w * y0.w;
      a01 += x0.x * y1.x + x0.y * y1.y + x0.z * y1.z + x0.w * y1.w;
      a10 += x1.x * y0.x + x1.y * y0.y + x1.z * y0.z + x1.w * y0.w;
      a11 += x1.x * y1.x + x1.y * y1.y + x1.z * y1.z + x1.w * y1.w;
    }
  }
  int c0 = ct * 32 + ox;
  if (!isQ) {
    int row0 = rt * 32 + oy;
    K2[(size_t)row0 * 512 + c0]           = a00 + 64.f * bk[c0];
    K2[(size_t)row0 * 512 + c0 + 1]       = a01 + 64.f * bk[c0 + 1];
    K2[(size_t)(row0 + 1) * 512 + c0]     = a10 + 64.f * bk[c0];
    K2[(size_t)(row0 + 1) * 512 + c0 + 1] = a11 + 64.f * bk[c0 + 1];
  } else if (oy < 8) {
    const float scale = 0.125f;
    qs[(size_t)oy * 512 + c0]           = (a00 + bq[c0]) * scale;
    qs[(size_t)oy * 512 + c0 + 1]       = (a01 + bq[c0 + 1]) * scale;
    qs[(size_t)(oy + 1) * 512 + c0]     = (a10 + bq[c0]) * scale;
    qs[(size_t)(oy + 1) * 512 + c0 + 1] = (a11 + bq[c0 + 1]) * scale;
  }
}

// ---------------- kernel 4: fused V-GEMM x2 slabs + softmax + PV -------------
// grid 256 = slab-pair(32) * g(8), XCD-grouped; 512 threads = 8 waves, w = e.
// LDS 128KB: Xa [8 kc][64 j][128B] @0, Xb @64KB. Interleaved K-loop: per step
// 4 shared af loads + 8 ds_read + 32 MFMA. Vp overlays dead X-tiles after.
__global__ __launch_bounds__(512, 2) void k_fused(
    const unsigned short* __restrict__ XT, const unsigned short* __restrict__ Wvb,
    const float* __restrict__ K2, const float* __restrict__ qs,
    const float* __restrict__ bv, float* __restrict__ out) {
  int p = blockIdx.x;
  int xcd = p & 7, idx = p >> 3;              // idx in [0,32)
  int sp = xcd * 4 + (idx & 3);               // slab pair [0,32)
  int g = idx >> 2;                           // [0,8)
  int slab0 = sp * 2, slab1 = slab0 + 1;      // same b (pair-aligned)
  int b = sp >> 2;
  int n0 = slab0 & 7, n1 = slab1 & 7;

  int tid = threadIdx.x;
  int w = tid >> 6, l = tid & 63;
  int l15 = l & 15, l4 = l >> 4, lr = l >> 3, lc = l & 7;

  __shared__ __align__(16) unsigned char smem[131072];

  const unsigned swzel = (unsigned)((lc ^ lr) << 3);  // pre-swizzled src col
  const unsigned short* xsrc0 = XT + (size_t)slab0 * 512 * 512;
  const unsigned short* xsrc1 = XT + (size_t)slab1 * 512 * 512;
  const unsigned short* wbase = Wvb + (size_t)(w * 64 + l15) * 512 + l4 * 8;
  const int brow = 8 * (w * 8 + lr) + g;

  // ---- stage both X-tiles: 16 x global_load_lds (16B) per thread ----
#pragma unroll
  for (int i = 0; i < 8; ++i)
    gload16(xsrc0 + (size_t)brow * 512 + i * 64 + swzel,
            smem + i * 8192 + w * 1024);
#pragma unroll
  for (int i = 0; i < 8; ++i)
    gload16(xsrc1 + (size_t)brow * 512 + i * 64 + swzel,
            smem + 65536 + i * 8192 + w * 1024);

  float alpha = qs[(size_t)b * 512 + w * 64 + l];               // lane = qq
  float beta0 = K2[(size_t)(slab0 * 8 + g) * 512 + w * 64 + l]; // lane = kk
  float beta1 = K2[(size_t)(slab1 * 8 + g) * 512 + w * 64 + l];
  float bvreg = bv[w * 64 + l];                                 // lane = kk

  f32x4_t acc0[4][4], acc1[4][4];
#pragma unroll
  for (int i = 0; i < 4; ++i)
#pragma unroll
    for (int j = 0; j < 4; ++j) {
      acc0[i][j] = (f32x4_t){0.f, 0.f, 0.f, 0.f};
      acc1[i][j] = (f32x4_t){0.f, 0.f, 0.f, 0.f};
    }

  __syncthreads();   // both tiles resident for the whole K-loop

  // ---- interleaved K-loop: 16 steps, 32 MFMA/step, shared af, depth-2 ----
  bf16x8_t af[2][4];
#pragma unroll
  for (int mt = 0; mt < 4; ++mt)
    af[0][mt] = *(const bf16x8_t*)(wbase + mt * 16 * 512);

#pragma unroll
  for (int s = 0; s < 16; ++s) {
    if (s < 15) {
#pragma unroll
      for (int mt = 0; mt < 4; ++mt)
        af[(s + 1) & 1][mt] =
            *(const bf16x8_t*)(wbase + mt * 16 * 512 + (s + 1) * 32);
    }
    unsigned colx = (unsigned)((s & 1) * 64 + l4 * 16);
    unsigned char* Ba = smem + (s >> 1) * 8192;
    unsigned char* Bb = smem + 65536 + (s >> 1) * 8192;
    bf16x8_t b0[4], b1[4];
#pragma unroll
    for (int nt = 0; nt < 4; ++nt) {
      unsigned row = (unsigned)(nt * 16 + l15);
      unsigned off = row * 128 + (colx ^ ((row & 7) << 4));
      b0[nt] = *(const bf16x8_t*)(Ba + off);
      b1[nt] = *(const bf16x8_t*)(Bb + off);
    }
#pragma unroll
    for (int mt = 0; mt < 4; ++mt)
#pragma unroll
      for (int nt = 0; nt < 4; ++nt)
        acc0[mt][nt] = __builtin_amdgcn_mfma_f32_16x16x32_bf16(
            af[s & 1][mt], b0[nt], acc0[mt][nt], 0, 0, 0);
#pragma unroll
    for (int mt = 0; mt < 4; ++mt)
#pragma unroll
      for (int nt = 0; nt < 4; ++nt)
        acc1[mt][nt] = __builtin_amdgcn_mfma_f32_16x16x32_bf16(
            af[s & 1][mt], b1[nt], acc1[mt][nt], 0, 0, 0);
  }

  __syncthreads();   // all waves done reading both X-tiles; safe to overlay

  // ---- per-slab: spill V -> wave-private LDS, softmax, PV, store ----
  // acc[mt][nt] reg r: kk = mt*16 + l4*4 + r, dd = nt*16 + l15.
#define SLAB_TAIL(ACC, VPOFF, BETA, NN)                                        \
  do {                                                                         \
    unsigned char* Vp = smem + (VPOFF) + w * 8192;                             \
    _Pragma("unroll")                                                          \
    for (int mt = 0; mt < 4; ++mt) {                                           \
      float bq0 = __shfl(bvreg, mt * 16 + l4 * 4 + 0);                         \
      float bq1 = __shfl(bvreg, mt * 16 + l4 * 4 + 1);                         \
      float bq2 = __shfl(bvreg, mt * 16 + l4 * 4 + 2);                         \
      float bq3 = __shfl(bvreg, mt * 16 + l4 * 4 + 3);                         \
      _Pragma("unroll")                                                        \
      for (int nt = 0; nt < 4; ++nt) {                                         \
        unsigned dd = (unsigned)(nt * 16 + l15);                               \
        uint2 pk;                                                              \
        pk.x = (unsigned)f2bf(ACC[mt][nt][0] + bq0) |                          \
               ((unsigned)f2bf(ACC[mt][nt][1] + bq1) << 16);                   \
        pk.y = (unsigned)f2bf(ACC[mt][nt][2] + bq2) |                          \
               ((unsigned)f2bf(ACC[mt][nt][3] + bq3) << 16);                   \
        *(uint2*)(Vp + dd * 128 +                                              \
                  ((unsigned)(mt * 32 + l4 * 8) ^ ((dd & 7) << 4))) = pk;      \
      }                                                                        \
    }                                                                          \
    float bmax = (BETA), bmin = (BETA);                                        \
    _Pragma("unroll")                                                          \
    for (int o = 32; o >= 1; o >>= 1) {                                        \
      bmax = fmaxf(bmax, __shfl_xor(bmax, o));                                 \
      bmin = fminf(bmin, __shfl_xor(bmin, o));                                 \
    }                                                                          \
    float m = alpha >= 0.f ? alpha * bmax : alpha * bmin;                      \
    float ssum = 0.f;                                                          \
    _Pragma("unroll 8")                                                        \
    for (int kk = 0; kk < 64; ++kk)                                            \
      ssum += __expf(fmaf(alpha, __shfl((BETA), kk), -m));                     \
    float inv = 1.0f / ssum;                                                   \
    f32x4_t acc2[4][4];                                                        \
    _Pragma("unroll")                                                          \
    for (int i = 0; i < 4; ++i)                                                \
      _Pragma("unroll")                                                        \
      for (int j = 0; j < 4; ++j) acc2[i][j] = (f32x4_t){0.f, 0.f, 0.f, 0.f};  \
    _Pragma("unroll")                                                          \
    for (int ks = 0; ks < 2; ++ks) {                                           \
      bf16x8_t va[4];                                                          \
      _Pragma("unroll")                                                        \
      for (int mt = 0; mt < 4; ++mt) {                                         \
        unsigned dd = (unsigned)(mt * 16 + l15);                               \
        va[mt] = *(const bf16x8_t*)(Vp + dd * 128 +                            \
                  ((unsigned)(ks * 64 + l4 * 16) ^ ((dd & 7) << 4)));          \
      }                                                                        \
      float bvv[8];                                                            \
      _Pragma("unroll")                                                        \
      for (int i = 0; i < 8; ++i)                                              \
        bvv[i] = __shfl((BETA), ks * 32 + l4 * 8 + i);                         \
      bf16x8_t pb[4];                                                          \
      _Pragma("unroll")                                                        \
      for (int nt = 0; nt < 4; ++nt) {                                         \
        int qq = nt * 16 + l15;                                                \
        float aq = __shfl(alpha, qq);                                          \
        float mq = __shfl(m, qq);                                              \
        float iq = __shfl(inv, qq);                                            \
        bf16x8_t pp;                                                           \
        _Pragma("unroll")                                                      \
        for (int i = 0; i < 8; ++i)                                            \
          pp[i] = (short)f2bf(__expf(fmaf(aq, bvv[i], -mq)) * iq);             \
        pb[nt] = pp;                                                           \
      }                                                                        \
      _Pragma("unroll")                                                        \
      for (int mt = 0; mt < 4; ++mt)                                           \
        _Pragma("unroll")                                                      \
        for (int nt = 0; nt < 4; ++nt)                                         \
          acc2[mt][nt] = __builtin_amdgcn_mfma_f32_16x16x32_bf16(              \
              va[mt], pb[nt], acc2[mt][nt], 0, 0, 0);                          \
    }                                                                          \
    _Pragma("unroll")                                                          \
    for (int mt = 0; mt < 4; ++mt) {                                           \
      _Pragma("unroll")                                                        \
      for (int r = 0; r < 4; ++r) {                                            \
        int dd = mt * 16 + l4 * 4 + r;                                         \
        size_t base =                                                          \
            (((size_t)(b * 512 + (NN) * 64 + dd)) * 64 + (g * 8 + w)) * 64;    \
        _Pragma("unroll")                                                      \
        for (int nt = 0; nt < 4; ++nt)                                         \
          out[base + nt * 16 + l15] = acc2[mt][nt][r];                         \
      }                                                                        \
    }                                                                          \
  } while (0)

  SLAB_TAIL(acc0, 0, beta0, n0);
  SLAB_TAIL(acc1, 65536, beta1, n1);
#undef SLAB_TAIL
}

// ---------------------------------------------------------------------------
extern "C" void kernel_launch(void* const* d_in, const int* in_sizes, int n_in,
                              void* d_out, int out_size, void* d_ws, size_t ws_size,
                              hipStream_t stream) {
  const float* guide = (const float*)d_in[0];
  const float* hid   = (const float*)d_in[1];
  const float* Wq    = (const float*)d_in[2];
  const float* bq    = (const float*)d_in[3];
  const float* Wk    = (const float*)d_in[4];
  const float* bk    = (const float*)d_in[5];
  const float* Wv    = (const float*)d_in[6];
  const float* bv    = (const float*)d_in[7];
  float* out = (float*)d_out;

  char* ws = (char*)d_ws;
  unsigned short* XT  = (unsigned short*)(ws);             // 33,554,432 B
  unsigned short* Wvb = (unsigned short*)(ws + 33554432);  //    524,288 B
  float* hrsum        = (float*)(ws + 34078720);           //  1,048,576 B
  float* K2           = (float*)(ws + 35127296);           //  1,048,576 B
  float* qs           = (float*)(ws + 36175872);           //     16,384 B

  k_trans<<<1040, 256, 0, stream>>>(hid, XT, hrsum, Wv, Wvb);
  k_k2<<<272, 256, 0, stream>>>(hrsum, Wk, bk, guide, Wq, bq, K2, qs);
  k_fused<<<256, 512, 0, stream>>>(XT, Wvb, K2, qs, bv, out);
}